// Round 3
// baseline (545.959 us; speedup 1.0000x reference)
//
#include <hip/hip_runtime.h>

// Brute N^2 neighborlist (upper-triangular pairs), N=6000, P=17,997,000.
// Output layout (flat f32): [0,P) i | [P,2P) j | [2P,3P) d | [3P,6P) r_xyz.
//
// R3: every global store is wave-contiguous; r-triples redistributed via LDS.
// R4/R5: contiguous dwordx4 j-loads + nontemporal stores — measured NEUTRAL
// (load path was not the bottleneck).
// R6 (this round): MEASUREMENT ROUND. The kernel is launched TWICE
// (idempotent: second launch overwrites identical values, so the test still
// passes). dur_us(R6) - dur_us(R2) = the kernel's true duration K, which the
// rocprof top-5 (all ~272us poison fills) cannot show us. This disambiguates
// "kernel ~165us, 90us headroom" vs "kernel ~90us, at write-BW floor".
// Kernel body is byte-identical to R2.

constexpr int NPART  = 6000;
constexpr int NPAIRS = 17997000;     // N*(N-1)/2; % 1024 == 200, % 4 == 0
constexpr float CUT  = 0.5f;
constexpr int TPB = 256;
constexpr int PPT = 4;               // pairs per thread
constexpr int PPB = TPB * PPT;       // 1024 pairs per block

typedef float fvec4 __attribute__((ext_vector_type(4)));

__device__ __forceinline__ int row_start(int i) {
    // pairs before row i: S(i) = i*(N-1) - i*(i-1)/2  (fits int32)
    return i * (NPART - 1) - (i * (i - 1)) / 2;
}

// numpy remainder(r+h, b) - h for |r| < b, b > 0, h = b/2 — bitwise-exact.
__device__ __forceinline__ float pbc_wrap(float r, float b, float h) {
    float v = __fadd_rn(r, h);
    if (v >= b)       v = __fsub_rn(v, b);
    else if (v < 0.f) v = __fadd_rn(v, b);
    return __fsub_rn(v, h);
}

__global__ __launch_bounds__(TPB) void nbl_kernel(
    const float* __restrict__ pos,     // [N,3]
    const float* __restrict__ boxv,    // [3,3]
    const int*  __restrict__ is_per,
    float* __restrict__ out)
{
    __shared__ float lds_r[PPB * 3];   // 12,288 B, final r layout for this block

    const int t     = threadIdx.x;
    const int pbase = blockIdx.x * PPB;
    const int p     = pbase + t * PPT;
    // nvalid is 1024 or 200 — always % 4 == 0, so each thread's 4 pairs are
    // entirely valid or entirely invalid.
    const int nvalid = (NPAIRS - pbase < PPB) ? (NPAIRS - pbase) : PPB;

    if (t * PPT < nvalid) {
        // invert triangular index (fp32 estimate + int fixup)
        const float A = 2.0f * NPART - 1.0f;   // 11999
        float disc = A * A - 8.0f * (float)p;
        int i = (int)((A - sqrtf(disc)) * 0.5f);
        if (i < 0) i = 0;
        if (i > NPART - 2) i = NPART - 2;
        while (i < NPART - 2 && row_start(i + 1) <= p) ++i;
        while (i > 0 && row_start(i) > p) --i;
        int j = i + 1 + (p - row_start(i));

        const bool per = (*is_per != 0);
        const float bx = boxv[0], by = boxv[4], bz = boxv[8];
        const float hx = __fmul_rn(bx, 0.5f);
        const float hy = __fmul_rn(by, 0.5f);
        const float hz = __fmul_rn(bz, 0.5f);

        float oi[4], oj[4], od[4], orr[12];

        if (j + PPT - 1 < NPART) {
            // FAST PATH (99.87% of threads): all 4 pairs stay in row i, so
            // rows j..j+3 are bytes [12j, 12j+48) — contiguous. 3x dwordx4.
            // Max read: j=5996 -> byte 72000 == end of pos buffer, in bounds.
            const float xi = pos[3 * i + 0];
            const float yi = pos[3 * i + 1];
            const float zi = pos[3 * i + 2];
            fvec4 va, vb, vc;
            __builtin_memcpy(&va, pos + 3 * j + 0, 16);  // jx jy jz  j1x
            __builtin_memcpy(&vb, pos + 3 * j + 4, 16);  // j1y j1z j2x j2y
            __builtin_memcpy(&vc, pos + 3 * j + 8, 16);  // j2z j3x j3y j3z
            const float xj[4] = {va.x, va.w, vb.z, vc.y};
            const float yj[4] = {va.y, vb.x, vb.w, vc.z};
            const float zj[4] = {va.z, vb.y, vc.x, vc.w};
            const float fi = (float)i;

            #pragma unroll
            for (int k = 0; k < 4; ++k) {
                float rx = __fsub_rn(xi, xj[k]);
                float ry = __fsub_rn(yi, yj[k]);
                float rz = __fsub_rn(zi, zj[k]);
                if (per) {
                    rx = pbc_wrap(rx, bx, hx);
                    ry = pbc_wrap(ry, by, hy);
                    rz = pbc_wrap(rz, bz, hz);
                }
                float s = __fadd_rn(__fadd_rn(__fmul_rn(rx, rx), __fmul_rn(ry, ry)),
                                    __fmul_rn(rz, rz));
                float d = __fsqrt_rn(s);
                bool in = (d <= CUT);

                oi[k] = in ? fi : -1.0f;
                oj[k] = in ? (float)(j + k) : -1.0f;
                od[k] = in ? d : 0.0f;
                orr[3 * k + 0] = in ? rx : 0.0f;
                orr[3 * k + 1] = in ? ry : 0.0f;
                orr[3 * k + 2] = in ? rz : 0.0f;
            }
        } else {
            // SLOW PATH: row wrap inside the 4-pair group (or j >= 5997).
            float xi = pos[3 * i + 0], yi = pos[3 * i + 1], zi = pos[3 * i + 2];
            #pragma unroll
            for (int k = 0; k < 4; ++k) {
                float xj = pos[3 * j + 0], yj = pos[3 * j + 1], zj = pos[3 * j + 2];
                float rx = __fsub_rn(xi, xj);
                float ry = __fsub_rn(yi, yj);
                float rz = __fsub_rn(zi, zj);
                if (per) {
                    rx = pbc_wrap(rx, bx, hx);
                    ry = pbc_wrap(ry, by, hy);
                    rz = pbc_wrap(rz, bz, hz);
                }
                float s = __fadd_rn(__fadd_rn(__fmul_rn(rx, rx), __fmul_rn(ry, ry)),
                                    __fmul_rn(rz, rz));
                float d = __fsqrt_rn(s);
                bool in = (d <= CUT);

                oi[k] = in ? (float)i : -1.0f;
                oj[k] = in ? (float)j : -1.0f;
                od[k] = in ? d : 0.0f;
                orr[3 * k + 0] = in ? rx : 0.0f;
                orr[3 * k + 1] = in ? ry : 0.0f;
                orr[3 * k + 2] = in ? rz : 0.0f;

                // advance to next upper-triangular pair
                ++j;
                if (j == NPART) { ++i; j = i + 1;
                    xi = pos[3 * i + 0]; yi = pos[3 * i + 1]; zi = pos[3 * i + 2]; }
            }
        }

        // stage r-triples in LDS in final layout (16B-aligned b128 writes;
        // 8 lanes cover all 32 banks once -> conflict-free serialization)
        fvec4* lv = (fvec4*)(lds_r + 12 * t);
        lv[0] = (fvec4){orr[0], orr[1], orr[2],  orr[3]};
        lv[1] = (fvec4){orr[4], orr[5], orr[6],  orr[7]};
        lv[2] = (fvec4){orr[8], orr[9], orr[10], orr[11]};

        // i/j/d streams: wave-contiguous float4, streaming (never re-read,
        // 432 MB >> 32 MB L2) -> nontemporal
        __builtin_nontemporal_store((fvec4){oi[0], oi[1], oi[2], oi[3]},
                                    (fvec4*)(out + p));
        __builtin_nontemporal_store((fvec4){oj[0], oj[1], oj[2], oj[3]},
                                    (fvec4*)(out + NPAIRS + p));
        __builtin_nontemporal_store((fvec4){od[0], od[1], od[2], od[3]},
                                    (fvec4*)(out + 2 * NPAIRS + p));
    }

    __syncthreads();

    // stream r out lane-contiguously: block owns floats [3*pbase, 3*pbase+3*nvalid)
    // 3*pbase % 4 == 0, 3*nvalid % 4 == 0 -> float4 granularity exact.
    const int nf4 = (3 * nvalid) / 4;                 // 768 or 150
    fvec4* rdst = (fvec4*)(out + 3 * NPAIRS + 3 * pbase);
    const fvec4* rsrc = (const fvec4*)lds_r;
    #pragma unroll
    for (int s = 0; s < 3; ++s) {
        int q = t + TPB * s;
        if (q < nf4) __builtin_nontemporal_store(rsrc[q], rdst + q);
    }
}

extern "C" void kernel_launch(void* const* d_in, const int* in_sizes, int n_in,
                              void* d_out, int out_size, void* d_ws, size_t ws_size,
                              hipStream_t stream) {
    const float* pos    = (const float*)d_in[0];
    const float* boxv   = (const float*)d_in[1];
    const int*   is_per = (const int*)d_in[2];
    float* out = (float*)d_out;

    const int grid = (NPAIRS + PPB - 1) / PPB;   // 17,576
    // MEASUREMENT: launch twice (idempotent). dur_us(this) - dur_us(prev)
    // isolates the kernel's true duration from the harness's fill/overhead.
    nbl_kernel<<<grid, TPB, 0, stream>>>(pos, boxv, is_per, out);
    nbl_kernel<<<grid, TPB, 0, stream>>>(pos, boxv, is_per, out);
}

// Round 4
// 441.980 us; speedup vs baseline: 1.2353x; 1.2353x over previous
//
#include <hip/hip_runtime.h>

// Brute N^2 neighborlist (upper-triangular pairs), N=6000, P=17,997,000.
// Output layout (flat f32): [0,P) i | [P,2P) j | [2P,3P) d | [3P,6P) r_xyz.
//
// R3: every global store is wave-contiguous; r-triples redistributed via LDS.
// R4/R5: contiguous dwordx4 j-loads + nontemporal stores — NEUTRAL.
// R6: double-launch measurement -> kernel K = 546-445 = 101 us vs 69 us
//     write floor (432 MB @ 6.2 TB/s, the fill's own rate).
// R7 (this round): __syncthreads() compiles to s_waitcnt vmcnt(0) + s_barrier,
// forcing every wave to wait for its i/j/d NT stores to COMPLETE in HBM
// (~600-900 cy) before the LDS copy-out — the store pipe idles in bursts
// every block (~30% duty-cycle loss = the 101-vs-69 gap). Fix: move the
// i/j/d stores AFTER the barrier (values live in registers). Pre-barrier
// there are no outstanding VMEM stores, so the barrier wait is a cheap
// lgkmcnt(0); post-barrier each wave fires all 6 stores and ends (s_endpgm
// does not wait on store completion) -> continuous store stream.
// PBC wrap replicates numpy remainder bitwise (Sterbenz-exact branches);
// explicit _rn intrinsics forbid contraction so the d<=0.5 mask cannot flip.

constexpr int NPART  = 6000;
constexpr int NPAIRS = 17997000;     // N*(N-1)/2; % 1024 == 200, % 4 == 0
constexpr float CUT  = 0.5f;
constexpr int TPB = 256;
constexpr int PPT = 4;               // pairs per thread
constexpr int PPB = TPB * PPT;       // 1024 pairs per block

typedef float fvec4 __attribute__((ext_vector_type(4)));

__device__ __forceinline__ int row_start(int i) {
    // pairs before row i: S(i) = i*(N-1) - i*(i-1)/2  (fits int32)
    return i * (NPART - 1) - (i * (i - 1)) / 2;
}

// numpy remainder(r+h, b) - h for |r| < b, b > 0, h = b/2 — bitwise-exact.
__device__ __forceinline__ float pbc_wrap(float r, float b, float h) {
    float v = __fadd_rn(r, h);
    if (v >= b)       v = __fsub_rn(v, b);
    else if (v < 0.f) v = __fadd_rn(v, b);
    return __fsub_rn(v, h);
}

__global__ __launch_bounds__(TPB) void nbl_kernel(
    const float* __restrict__ pos,     // [N,3]
    const float* __restrict__ boxv,    // [3,3]
    const int*  __restrict__ is_per,
    float* __restrict__ out)
{
    __shared__ float lds_r[PPB * 3];   // 12,288 B, final r layout for this block

    const int t     = threadIdx.x;
    const int pbase = blockIdx.x * PPB;
    const int p     = pbase + t * PPT;
    // nvalid is 1024 or 200 — always % 4 == 0, so each thread's 4 pairs are
    // entirely valid or entirely invalid.
    const int nvalid = (NPAIRS - pbase < PPB) ? (NPAIRS - pbase) : PPB;
    const bool active = (t * PPT < nvalid);

    float oi[4], oj[4], od[4];

    if (active) {
        // invert triangular index (fp32 estimate + int fixup)
        const float A = 2.0f * NPART - 1.0f;   // 11999
        float disc = A * A - 8.0f * (float)p;
        int i = (int)((A - sqrtf(disc)) * 0.5f);
        if (i < 0) i = 0;
        if (i > NPART - 2) i = NPART - 2;
        while (i < NPART - 2 && row_start(i + 1) <= p) ++i;
        while (i > 0 && row_start(i) > p) --i;
        int j = i + 1 + (p - row_start(i));

        const bool per = (*is_per != 0);
        const float bx = boxv[0], by = boxv[4], bz = boxv[8];
        const float hx = __fmul_rn(bx, 0.5f);
        const float hy = __fmul_rn(by, 0.5f);
        const float hz = __fmul_rn(bz, 0.5f);

        float orr[12];

        if (j + PPT - 1 < NPART) {
            // FAST PATH (99.87% of threads): all 4 pairs stay in row i, so
            // rows j..j+3 are bytes [12j, 12j+48) — contiguous. 3x dwordx4.
            // Max read: j=5996 -> byte 72000 == end of pos buffer, in bounds.
            const float xi = pos[3 * i + 0];
            const float yi = pos[3 * i + 1];
            const float zi = pos[3 * i + 2];
            fvec4 va, vb, vc;
            __builtin_memcpy(&va, pos + 3 * j + 0, 16);  // jx jy jz  j1x
            __builtin_memcpy(&vb, pos + 3 * j + 4, 16);  // j1y j1z j2x j2y
            __builtin_memcpy(&vc, pos + 3 * j + 8, 16);  // j2z j3x j3y j3z
            const float xj[4] = {va.x, va.w, vb.z, vc.y};
            const float yj[4] = {va.y, vb.x, vb.w, vc.z};
            const float zj[4] = {va.z, vb.y, vc.x, vc.w};
            const float fi = (float)i;

            #pragma unroll
            for (int k = 0; k < 4; ++k) {
                float rx = __fsub_rn(xi, xj[k]);
                float ry = __fsub_rn(yi, yj[k]);
                float rz = __fsub_rn(zi, zj[k]);
                if (per) {
                    rx = pbc_wrap(rx, bx, hx);
                    ry = pbc_wrap(ry, by, hy);
                    rz = pbc_wrap(rz, bz, hz);
                }
                float s = __fadd_rn(__fadd_rn(__fmul_rn(rx, rx), __fmul_rn(ry, ry)),
                                    __fmul_rn(rz, rz));
                float d = __fsqrt_rn(s);
                bool in = (d <= CUT);

                oi[k] = in ? fi : -1.0f;
                oj[k] = in ? (float)(j + k) : -1.0f;
                od[k] = in ? d : 0.0f;
                orr[3 * k + 0] = in ? rx : 0.0f;
                orr[3 * k + 1] = in ? ry : 0.0f;
                orr[3 * k + 2] = in ? rz : 0.0f;
            }
        } else {
            // SLOW PATH: row wrap inside the 4-pair group (or j >= 5997).
            float xi = pos[3 * i + 0], yi = pos[3 * i + 1], zi = pos[3 * i + 2];
            #pragma unroll
            for (int k = 0; k < 4; ++k) {
                float xj = pos[3 * j + 0], yj = pos[3 * j + 1], zj = pos[3 * j + 2];
                float rx = __fsub_rn(xi, xj);
                float ry = __fsub_rn(yi, yj);
                float rz = __fsub_rn(zi, zj);
                if (per) {
                    rx = pbc_wrap(rx, bx, hx);
                    ry = pbc_wrap(ry, by, hy);
                    rz = pbc_wrap(rz, bz, hz);
                }
                float s = __fadd_rn(__fadd_rn(__fmul_rn(rx, rx), __fmul_rn(ry, ry)),
                                    __fmul_rn(rz, rz));
                float d = __fsqrt_rn(s);
                bool in = (d <= CUT);

                oi[k] = in ? (float)i : -1.0f;
                oj[k] = in ? (float)j : -1.0f;
                od[k] = in ? d : 0.0f;
                orr[3 * k + 0] = in ? rx : 0.0f;
                orr[3 * k + 1] = in ? ry : 0.0f;
                orr[3 * k + 2] = in ? rz : 0.0f;

                // advance to next upper-triangular pair
                ++j;
                if (j == NPART) { ++i; j = i + 1;
                    xi = pos[3 * i + 0]; yi = pos[3 * i + 1]; zi = pos[3 * i + 2]; }
            }
        }

        // stage r-triples in LDS in final layout (16B-aligned b128 writes;
        // 8 lanes cover all 32 banks once -> conflict-free serialization).
        // NO global stores before the barrier: keeps the barrier's implicit
        // s_waitcnt down to lgkmcnt(0) (LDS only, ~tens of cycles).
        fvec4* lv = (fvec4*)(lds_r + 12 * t);
        lv[0] = (fvec4){orr[0], orr[1], orr[2],  orr[3]};
        lv[1] = (fvec4){orr[4], orr[5], orr[6],  orr[7]};
        lv[2] = (fvec4){orr[8], orr[9], orr[10], orr[11]};
    }

    __syncthreads();

    // All global stores issue here, back-to-back, with nothing waiting on
    // their completion (s_endpgm does not drain the store queue) -> the
    // per-CU store stream runs continuously across blocks.
    if (active) {
        __builtin_nontemporal_store((fvec4){oi[0], oi[1], oi[2], oi[3]},
                                    (fvec4*)(out + p));
        __builtin_nontemporal_store((fvec4){oj[0], oj[1], oj[2], oj[3]},
                                    (fvec4*)(out + NPAIRS + p));
        __builtin_nontemporal_store((fvec4){od[0], od[1], od[2], od[3]},
                                    (fvec4*)(out + 2 * NPAIRS + p));
    }

    // stream r out lane-contiguously: block owns floats [3*pbase, 3*pbase+3*nvalid)
    // 3*pbase % 4 == 0, 3*nvalid % 4 == 0 -> float4 granularity exact.
    const int nf4 = (3 * nvalid) / 4;                 // 768 or 150
    fvec4* rdst = (fvec4*)(out + 3 * NPAIRS + 3 * pbase);
    const fvec4* rsrc = (const fvec4*)lds_r;
    #pragma unroll
    for (int s = 0; s < 3; ++s) {
        int q = t + TPB * s;
        if (q < nf4) __builtin_nontemporal_store(rsrc[q], rdst + q);
    }
}

extern "C" void kernel_launch(void* const* d_in, const int* in_sizes, int n_in,
                              void* d_out, int out_size, void* d_ws, size_t ws_size,
                              hipStream_t stream) {
    const float* pos    = (const float*)d_in[0];
    const float* boxv   = (const float*)d_in[1];
    const int*   is_per = (const int*)d_in[2];
    float* out = (float*)d_out;

    const int grid = (NPAIRS + PPB - 1) / PPB;   // 17,576
    nbl_kernel<<<grid, TPB, 0, stream>>>(pos, boxv, is_per, out);
}